// Round 3
// baseline (180.461 us; speedup 1.0000x reference)
//
#include <hip/hip_runtime.h>

// Problem constants (from reference setup_inputs)
#define B 8
#define C 64
#define H 152
#define W 272
#define HW (H * W)          // 41344
#define K 500
#define KP 512              // K padded to tile multiple
#define ALPHA 0.25f
#define PROB_MIN 1e-4f

typedef __attribute__((ext_vector_type(8))) short short8;   // 8 bf16 (4 VGPRs)
typedef __attribute__((ext_vector_type(4))) float floatx4;  // 4 fp32 acc

// fp32 -> bf16 round-to-nearest-even
__device__ __forceinline__ unsigned short f32_to_bf16(float f) {
    union { float f; unsigned int u; } v; v.f = f;
    unsigned int r = v.u + 0x7FFFu + ((v.u >> 16) & 1u);
    return (unsigned short)(r >> 16);
}

// ---------------------------------------------------------------------------
// Kernel 1: masked gather -> bf16 feats [B, KP, C]; zero-pads rows K..KP-1.
// Plane-local layout: one workgroup per (b, c, cur/pre) channel plane, so all
// scattered reads stay inside a 165 KB window (DRAM row + TLB locality),
// idx/mask loads are coalesced, strided 2B feat writes merge in L2 (1 MB tot).
// Also zero-initializes the scalar output (poisoned 0xAA before replay).
// ---------------------------------------------------------------------------
__global__ __launch_bounds__(256) void gather_kernel(
    const float* __restrict__ cur_reid,
    const float* __restrict__ pre_reid,
    const int* __restrict__ cur_inds,
    const int* __restrict__ pre_inds,
    const int* __restrict__ cur_circ,
    const int* __restrict__ pre_circ,
    const int* __restrict__ tmask,
    unsigned short* __restrict__ curf,
    unsigned short* __restrict__ pref,
    float* __restrict__ out)
{
    const int c   = blockIdx.x;     // 0..C-1
    const int b   = blockIdx.y;     // 0..B-1
    const int arr = blockIdx.z;     // 0: cur, 1: pre
    const int t   = threadIdx.x;    // 0..255

    if (c == 0 && b == 0 && arr == 0 && t == 0)
        out[0] = 0.0f;              // before loss kernel (stream order)

    const float* plane = (arr ? pre_reid : cur_reid) + ((size_t)(b * C + c)) * HW;
    const int* inds = arr ? pre_inds : cur_inds;
    const int* circ = arr ? pre_circ : cur_circ;
    unsigned short* feat = arr ? pref : curf;

#pragma unroll
    for (int r = 0; r < 2; ++r) {   // 2*256 = 512 = KP (covers zero padding)
        const int k = t + r * 256;
        unsigned short v = 0;
        if (k < K) {
            const int bk  = b * K + k;
            const int idx = tmask[bk] ? inds[bk] : circ[bk];
            v = f32_to_bf16(plane[idx]);
        }
        feat[((size_t)(b * KP + k)) * C + c] = v;
    }
}

// ---------------------------------------------------------------------------
// Kernel 2: per-wave 16x16 tile of sim via MFMA 16x16x32 bf16 (2 MFMAs, K=64),
// fragments loaded directly from global (feat fits in L1/L2), fused focal
// loss + block reduce + one atomicAdd per block.
// ---------------------------------------------------------------------------
__device__ __forceinline__ float focal_term(float x, int gi, int gj, int b,
                                            const int* __restrict__ tmask)
{
    if (gi >= K || gj >= K) return 0.0f;
    const float sim = 1.0f / (1.0f + __expf(-x));
    const int gt = (gi == gj) ? tmask[b * K + gi] : 0;
    float p = gt ? sim : 1.0f - sim;
    p = fminf(fmaxf(p, PROB_MIN), 1.0f);
    const float a = gt ? ALPHA : (1.0f - ALPHA);
    const float om = 1.0f - p;
    return a * om * om * (-__logf(p));
}

#define LOSS_THREADS 1024   // 16 waves per block -> 16 tiles per block

__global__ __launch_bounds__(LOSS_THREADS) void loss_kernel(
    const unsigned short* __restrict__ curf,
    const unsigned short* __restrict__ pref,
    const int* __restrict__ tmask,
    float* __restrict__ out)
{
    __shared__ float wsum[LOSS_THREADS / 64];

    const int t    = threadIdx.x;
    const int wave = t >> 6;
    const int lane = t & 63;

    // Flat tile id -> (b, ti, tj); tiles: 32 x 32 per batch, 8 batches = 8192.
    const int tile = blockIdx.x * (LOSS_THREADS / 64) + wave;
    const int b    = tile >> 10;
    const int rem  = tile & 1023;
    const int ti   = rem >> 5;
    const int tj   = rem & 31;

    const int m16  = lane & 15;   // A-row / B-row (=sim col) within tile
    const int quad = lane >> 4;   // 0..3

    // A frag: curf[b][ti*16 + m16][quad*8 + (0..7)]  (+32 for second MFMA)
    const unsigned short* pa = curf + (((size_t)(b * KP + ti * 16 + m16)) * C + quad * 8);
    const unsigned short* pb = pref + (((size_t)(b * KP + tj * 16 + m16)) * C + quad * 8);
    const short8 a0 = *(const short8*)pa;
    const short8 a1 = *(const short8*)(pa + 32);
    const short8 b0 = *(const short8*)pb;
    const short8 b1 = *(const short8*)(pb + 32);

    floatx4 acc = {0.f, 0.f, 0.f, 0.f};
    acc = __builtin_amdgcn_mfma_f32_16x16x32_bf16(a0, b0, acc, 0, 0, 0);
    acc = __builtin_amdgcn_mfma_f32_16x16x32_bf16(a1, b1, acc, 0, 0, 0);

    // C/D layout: col = lane&15, row = quad*4 + reg   [measured m89/m91]
    const int gj = tj * 16 + m16;
    float s = 0.f;
#pragma unroll
    for (int r = 0; r < 4; ++r) {
        const int gi = ti * 16 + quad * 4 + r;
        s += focal_term(acc[r], gi, gj, b, tmask);
    }

    // wave64 butterfly, then cross-wave via LDS, one atomic per block
#pragma unroll
    for (int o = 32; o > 0; o >>= 1) s += __shfl_down(s, o, 64);
    if (lane == 0) wsum[wave] = s;
    __syncthreads();
    if (t == 0) {
        float tot = 0.f;
#pragma unroll
        for (int w = 0; w < LOSS_THREADS / 64; ++w) tot += wsum[w];
        atomicAdd(out, tot * (1.0f / ((float)B * (float)K * (float)K)));
    }
}

// ---------------------------------------------------------------------------
extern "C" void kernel_launch(void* const* d_in, const int* in_sizes, int n_in,
                              void* d_out, int out_size, void* d_ws, size_t ws_size,
                              hipStream_t stream)
{
    const float* cur_reid = (const float*)d_in[0];
    const float* pre_reid = (const float*)d_in[1];
    const int*   cur_inds = (const int*)d_in[2];
    const int*   pre_inds = (const int*)d_in[3];
    const int*   cur_circ = (const int*)d_in[4];
    const int*   pre_circ = (const int*)d_in[5];
    const int*   tmask    = (const int*)d_in[6];
    float*       out      = (float*)d_out;

    unsigned short* curf = (unsigned short*)d_ws;            // B*KP*C bf16 = 512 KB
    unsigned short* pref = curf + (size_t)B * KP * C;        // another 512 KB

    dim3 ggrid(C, B, 2);
    gather_kernel<<<ggrid, 256, 0, stream>>>(
        cur_reid, pre_reid, cur_inds, pre_inds, cur_circ, pre_circ, tmask,
        curf, pref, out);

    // 8192 tiles (32x32x8) / 16 waves per block = 512 blocks
    loss_kernel<<<512, LOSS_THREADS, 0, stream>>>(curf, pref, tmask, out);
}